// Round 5
// baseline (91.425 us; speedup 1.0000x reference)
//
#include <hip/hip_runtime.h>

// FermiLayer fused kernel set for MI355X (gfx950).
// Inputs (f32): h1(768,256) h2(768,768,64) W1n(1216,256) b1n(256)
//               W1e(1216,256) b1e(256) W2(4,64,64) b2(4,64)
// Outputs (f32, concat): h1_out(768,256), h2_out(768,768,64)

#define H1OUT_ELEMS (768 * 256)

typedef short short8 __attribute__((ext_vector_type(8)));
typedef float f32x4 __attribute__((ext_vector_type(4)));

__device__ __forceinline__ unsigned short f2bf(float f) {
    unsigned u = __builtin_bit_cast(unsigned, f);
    unsigned r = u + 0x7fffu + ((u >> 16) & 1u);
    return (unsigned short)(r >> 16);
}

// out = (hv + gelu_rescaled(x)) / sqrt(2), tanh-approx gelu.
__device__ __forceinline__ float gelu_res(float x, float hv) {
    float x2 = x * x;
    float z = x * fmaf(-0.1029432196f, x2, -2.3025850930f);
    float e = __builtin_amdgcn_exp2f(z);
    float r = __builtin_amdgcn_rcpf(1.f + e);
    return fmaf(x * r, 1.2111740f, hv * 0.70710678f);
}

// ---------------------------------------------------------------------------
// Fused kernel 1:
//   blocks [0,12):    h1 per-64-row-tile column sums -> part1
//   blocks [12,316):  W1n/W1e transpose-convert -> WT bf16 (64k x 32e tiles)
//   blocks [316, +9216): h2 update (zero-LDS MFMA, transposed acc) + col sums
// ---------------------------------------------------------------------------
__global__ __launch_bounds__(256) void k_h2pre(
    const float* __restrict__ h2, const float* __restrict__ W2,
    const float* __restrict__ b2, const float* __restrict__ h1,
    const float* __restrict__ W1n, const float* __restrict__ W1e,
    float* __restrict__ out2, float* __restrict__ part2,
    float* __restrict__ part1, unsigned short* __restrict__ WT) {
    __shared__ union SM {
        float red[2][16][68];    // col-sum scratch (h2 path)   8704 B
        float tile2[64][33];     // W transpose tile (prefix)   8448 B
    } sm;

    int b = blockIdx.x;
    const int t = threadIdx.x;

    if (b < 12) {  // ---- h1 per-64-row-tile column sums ----
        float s = 0.f;
        #pragma unroll 8
        for (int r = 0; r < 64; ++r) s += h1[(size_t)(b * 64 + r) * 256 + t];
        part1[b * 256 + t] = s;
        return;
    }
    if (b < 316) {  // ---- W transpose-convert, 64(k) x 32(e) tiles ----
        int idx = b - 12;              // 0..303
        int mtx = idx / 152;
        int r2  = idx % 152;
        int k0 = (r2 >> 3) * 64, e0 = (r2 & 7) * 32;
        const float* W = mtx ? W1e : W1n;
        #pragma unroll
        for (int i = 0; i < 8; ++i) {
            int j = i * 256 + t;
            int kr = j >> 5, ec = j & 31;
            sm.tile2[kr][ec] = W[(size_t)(k0 + kr) * 256 + e0 + ec];
        }
        __syncthreads();
        int er = t >> 3, k8 = (t & 7) * 8;
        short8 o;
        #pragma unroll
        for (int j = 0; j < 8; ++j) o[j] = (short)f2bf(sm.tile2[k8 + j][er]);
        *reinterpret_cast<short8*>(
            &WT[((size_t)mtx * 256 + e0 + er) * 1216 + k0 + k8]) = o;
        return;
    }

    // ---- h2 update ----
    b -= 316;
    const int ct = b % 12;
    const int n  = b / 12;
    const int m0 = ct * 64;

    const int rs = (n < 128) ? 0 : ((n < 448) ? 1 : 2);
    const int cs = (ct < 2) ? 0 : ((ct < 7) ? 1 : 2);
    int p;
    if (rs == 0)      p = (cs == 0) ? 0 : 1;
    else if (rs == 1) p = (cs == 0) ? 1 : ((cs == 1) ? 2 : 3);
    else              p = (cs == 0) ? 1 : ((cs == 1) ? 3 : 2);

    const float* src = h2 + ((size_t)n * 768 + m0) * 64;
    const int lane = t & 63;
    const int wv = t >> 6;
    const int wm = wv >> 1, we = wv & 1;
    const int lr = lane & 15, lk = lane >> 4;

    // --- direct A fragment loads (f32, 8 x dwordx4, fully independent) ---
    const float* arow = src + (wm * 32 + lr) * 64 + lk * 8;
    float4 af[2][2][2];   // [fm][kh][half]
    #pragma unroll
    for (int fm = 0; fm < 2; ++fm)
        #pragma unroll
        for (int kh = 0; kh < 2; ++kh) {
            const float* pp = arow + fm * 1024 + kh * 32;
            af[fm][kh][0] = *reinterpret_cast<const float4*>(pp);
            af[fm][kh][1] = *reinterpret_cast<const float4*>(pp + 4);
        }

    // --- column partial sums into LDS (we==0 waves) ---
    if (we == 0) {
        #pragma unroll
        for (int kh = 0; kh < 2; ++kh) {
            float4 s0, s1;
            s0.x = af[0][kh][0].x + af[1][kh][0].x;
            s0.y = af[0][kh][0].y + af[1][kh][0].y;
            s0.z = af[0][kh][0].z + af[1][kh][0].z;
            s0.w = af[0][kh][0].w + af[1][kh][0].w;
            s1.x = af[0][kh][1].x + af[1][kh][1].x;
            s1.y = af[0][kh][1].y + af[1][kh][1].y;
            s1.z = af[0][kh][1].z + af[1][kh][1].z;
            s1.w = af[0][kh][1].w + af[1][kh][1].w;
            *reinterpret_cast<float4*>(&sm.red[wm][lr][kh * 32 + lk * 8]) = s0;
            *reinterpret_cast<float4*>(&sm.red[wm][lr][kh * 32 + lk * 8 + 4]) = s1;
        }
    }

    // --- convert A to bf16 fragments ---
    short8 aF[2][2];
    #pragma unroll
    for (int fm = 0; fm < 2; ++fm)
        #pragma unroll
        for (int kh = 0; kh < 2; ++kh) {
            short8 o;
            o[0] = (short)f2bf(af[fm][kh][0].x);
            o[1] = (short)f2bf(af[fm][kh][0].y);
            o[2] = (short)f2bf(af[fm][kh][0].z);
            o[3] = (short)f2bf(af[fm][kh][0].w);
            o[4] = (short)f2bf(af[fm][kh][1].x);
            o[5] = (short)f2bf(af[fm][kh][1].y);
            o[6] = (short)f2bf(af[fm][kh][1].z);
            o[7] = (short)f2bf(af[fm][kh][1].w);
            aF[fm][kh] = o;
        }

    // --- B fragments direct from W2 (scalar f32 columns, L1/L2-hot) ---
    const float* wp = W2 + p * 4096 + we * 32 + lr;
    short8 bF[2][2];   // [fe][kh]
    #pragma unroll
    for (int fe = 0; fe < 2; ++fe)
        #pragma unroll
        for (int kh = 0; kh < 2; ++kh) {
            const float* q = wp + fe * 16 + (kh * 32 + lk * 8) * 64;
            short8 o;
            #pragma unroll
            for (int j = 0; j < 8; ++j) o[j] = (short)f2bf(q[j * 64]);
            bF[fe][kh] = o;
        }

    // --- MFMA, operands SWAPPED -> transposed D: lane holds row m=..+lr,
    //     4 consecutive cols e=..+lk*4+r ---
    f32x4 acc[2][2] = {};   // [fm][fe]
    #pragma unroll
    for (int kh = 0; kh < 2; ++kh)
        #pragma unroll
        for (int fm = 0; fm < 2; ++fm)
            #pragma unroll
            for (int fe = 0; fe < 2; ++fe)
                acc[fm][fe] = __builtin_amdgcn_mfma_f32_16x16x32_bf16(
                    bF[fe][kh], aF[fm][kh], acc[fm][fe], 0, 0, 0);

    __syncthreads();

    // --- finalize per-tile column sums ---
    if (t < 64) {
        float s = 0.f;
        #pragma unroll
        for (int r = 0; r < 16; ++r) s += sm.red[0][r][t] + sm.red[1][r][t];
        part2[((size_t)n * 12 + ct) * 64 + t] = s;
    }

    // --- epilogue: fully vectorized float4 bias+gelu+residual+store ---
    float* dst = out2 + ((size_t)n * 768 + m0) * 64;
    #pragma unroll
    for (int fm = 0; fm < 2; ++fm) {
        const int mm = wm * 32 + fm * 16 + lr;
        #pragma unroll
        for (int fe = 0; fe < 2; ++fe) {
            const int ee = we * 32 + fe * 16 + lk * 4;
            f32x4 bias4 = *reinterpret_cast<const f32x4*>(b2 + p * 64 + ee);
            f32x4 hv = *reinterpret_cast<const f32x4*>(src + mm * 64 + ee);
            f32x4 o;
            o[0] = gelu_res(acc[fm][fe][0] + bias4[0], hv[0]);
            o[1] = gelu_res(acc[fm][fe][1] + bias4[1], hv[1]);
            o[2] = gelu_res(acc[fm][fe][2] + bias4[2], hv[2]);
            o[3] = gelu_res(acc[fm][fe][3] + bias4[3], hv[3]);
            __builtin_nontemporal_store(
                o, reinterpret_cast<f32x4*>(dst + mm * 64 + ee));
        }
    }
}

// ---------------------------------------------------------------------------
// Fused kernel 2: build feats rows (16) in LDS, then GEMM vs WT + epilogue.
// grid (48, 2), block 256 (4 waves; each wave 32 output cols). Swapped MFMA.
// ---------------------------------------------------------------------------
__global__ __launch_bounds__(256) void k_h1f(
    const float* __restrict__ h1, const unsigned short* __restrict__ WT,
    const float* __restrict__ part2, const float* __restrict__ part1,
    const float* __restrict__ b1n, const float* __restrict__ b1e,
    float* __restrict__ out1) {
    __shared__ unsigned short FL[16][1224];

    const int n0 = blockIdx.x * 16;
    const int half = blockIdx.y;
    const int t = threadIdx.x;
    const bool dn = (n0 >= 448);
    const bool nucl = (n0 < 128);

    // phase 1: h1 slice (cols 0..255)
    #pragma unroll
    for (int i = 0; i < 16; ++i) {
        int idx = i * 256 + t;
        int r = idx >> 8, c = idx & 255;
        FL[r][c] = f2bf(h1[(size_t)(n0 + r) * 256 + c]);
    }
    // phase 2: h2_mean (cols 256..447)
    #pragma unroll
    for (int i = 0; i < 12; ++i) {
        int idx = i * 256 + t;
        int r = idx / 192, c = idx % 192;
        int sec = c >> 6, d = c & 63;
        int s2 = (dn && sec >= 1) ? (3 - sec) : sec;
        const float* pr = part2 + (size_t)(n0 + r) * 768;
        float s;
        if (s2 == 0) {
            s = (pr[d] + pr[64 + d]) * (1.f / 128.f);
        } else {
            int q0 = (s2 == 1) ? 2 : 7;
            s = 0.f;
            #pragma unroll
            for (int q = 0; q < 5; ++q) s += pr[(q0 + q) * 64 + d];
            s *= (1.f / 320.f);
        }
        FL[r][256 + c] = f2bf(s);
    }
    // phase 3: h1_mean (cols 448..1215), shared across the 16 rows
    #pragma unroll
    for (int i = 0; i < 3; ++i) {
        int j = i * 256 + t;
        int sec = j >> 8, e2 = j & 255;
        int s2 = (dn && sec >= 1) ? (3 - sec) : sec;
        float s;
        if (s2 == 0) {
            s = (part1[e2] + part1[256 + e2]) * (1.f / 128.f);
        } else {
            int q0 = (s2 == 1) ? 2 : 7;
            s = 0.f;
            #pragma unroll
            for (int q = 0; q < 5; ++q) s += part1[(q0 + q) * 256 + e2];
            s *= (1.f / 320.f);
        }
        unsigned short bv = f2bf(s);
        #pragma unroll
        for (int r = 0; r < 16; ++r) FL[r][448 + j] = bv;
    }
    __syncthreads();

    const int w = t >> 6, lane = t & 63;
    const int lr = lane & 15, lk = lane >> 4;
    const int e0 = half * 128 + w * 32;
    const unsigned short* BT = WT + (nucl ? 0 : (size_t)256 * 1216);
    const unsigned short* br0 = BT + (size_t)(e0 + lr) * 1216 + lk * 8;
    const unsigned short* br1 = br0 + (size_t)16 * 1216;
    const unsigned short* ar = &FL[lr][lk * 8];

    f32x4 acc0 = {}, acc1 = {};
    #pragma unroll 2
    for (int k = 0; k < 1216; k += 32) {
        short8 aF = *reinterpret_cast<const short8*>(ar + k);
        short8 b0 = *reinterpret_cast<const short8*>(br0 + k);
        short8 b1 = *reinterpret_cast<const short8*>(br1 + k);
        acc0 = __builtin_amdgcn_mfma_f32_16x16x32_bf16(b0, aF, acc0, 0, 0, 0);
        acc1 = __builtin_amdgcn_mfma_f32_16x16x32_bf16(b1, aF, acc1, 0, 0, 0);
    }

    const float* bb = nucl ? b1n : b1e;
    const int m = n0 + lr;
    #pragma unroll
    for (int j = 0; j < 2; ++j) {
        const f32x4 a = j ? acc1 : acc0;
        int e = e0 + j * 16 + lk * 4;
        f32x4 bias4 = *reinterpret_cast<const f32x4*>(bb + e);
        f32x4 hv = *reinterpret_cast<const f32x4*>(h1 + (size_t)m * 256 + e);
        f32x4 o;
        o[0] = gelu_res(a[0] + bias4[0], hv[0]);
        o[1] = gelu_res(a[1] + bias4[1], hv[1]);
        o[2] = gelu_res(a[2] + bias4[2], hv[2]);
        o[3] = gelu_res(a[3] + bias4[3], hv[3]);
        *reinterpret_cast<f32x4*>(out1 + (size_t)m * 256 + e) = o;
    }
}

// ---------------------------------------------------------------------------
extern "C" void kernel_launch(void* const* d_in, const int* in_sizes, int n_in,
                              void* d_out, int out_size, void* d_ws, size_t ws_size,
                              hipStream_t stream) {
    const float* h1  = (const float*)d_in[0];
    const float* h2  = (const float*)d_in[1];
    const float* W1n = (const float*)d_in[2];
    const float* b1n = (const float*)d_in[3];
    const float* W1e = (const float*)d_in[4];
    const float* b1e = (const float*)d_in[5];
    const float* W2  = (const float*)d_in[6];
    const float* b2  = (const float*)d_in[7];

    float* out1 = (float*)d_out;             // h1_out: 768*256
    float* out2 = out1 + H1OUT_ELEMS;        // h2_out: 768*768*64

    float* part2 = (float*)d_ws;                                  // 768*12*64 f32
    float* part1 = part2 + 768 * 12 * 64;                         // 12*256 f32
    unsigned short* WT = (unsigned short*)(part1 + 12 * 256);     // 2*256*1216 bf16

    k_h2pre<<<dim3(316 + 12 * 768), 256, 0, stream>>>(
        h2, W2, b2, h1, W1n, W1e, out2, part2, part1, WT);
    k_h1f<<<dim3(48, 2), 256, 0, stream>>>(h1, WT, part2, part1, b1n, b1e, out1);
}